// Round 14
// baseline (204.754 us; speedup 1.0000x reference)
//
#include <hip/hip_runtime.h>
#include <math.h>

#define N_NODES 50000
#define N_EDGES 800000
#define D 64
#define CAP 48          // bucket capacity; deg ~ Binom(800k,1/50k), mean 16, P(>48) ~ 0
#define NPART 8         // node partitions == XCDs
#define PART_N (N_NODES / NPART)    // 6250
#define ACHUNK 2048     // edges per partition-phase block
#define NBLK_A ((N_EDGES + ACHUNK - 1) / ACHUNK)   // 391
#define SEG_CAP 448     // per-(block,part) segment capacity (mean 256, +12.8 sigma)
#define NB_PER_PART 32  // phase-B blocks per partition
#define CONV_BLKS 3125  // convert blocks in prep
#define BKTI_BLKS 2344  // bucket-init blocks in prep (int4 writes)

// ---------------- workspace layout (byte offsets, no aliasing) ----------------
// fb   @ 0        : 6.401 MB (bf16 rows 128B; 50001 rows, row 50000 = ZERO pad row;
//                             feats, then x2 (layer-2 out) ping-pong)
// hb   @ 6401024  : 6.401 MB (bf16 rows; 50001 rows, row 50000 = ZERO pad row;
//                             x1 (layer-1 out))
// stage @ 12802048 : 5.61 MB ; cntg @ 18433024 ; pos @ 19201024 ; bucket @ 19401728
// total 29.0 MB (<= 32.2 MB proven available)
#define FB_OFF   0
#define HB_OFF   6401024
#define STG_OFF  12802048
#define CNTG_OFF 18433024
#define POS_OFF  19201024
#define BKT_OFF  19401728

// ---- bf16 pack/unpack helpers (RNE) ----
__device__ __forceinline__ unsigned int bf_rtn(float x) {
    unsigned int b = __float_as_uint(x);
    return (b + 0x7fffu + ((b >> 16) & 1u)) >> 16;
}
__device__ __forceinline__ unsigned int bf2_pack(float lo, float hi) {
    return bf_rtn(lo) | (bf_rtn(hi) << 16);
}
__device__ __forceinline__ float4 bf4_unpack(uint2 q) {
    float4 r;
    r.x = __uint_as_float(q.x << 16);
    r.y = __uint_as_float(q.x & 0xffff0000u);
    r.z = __uint_as_float(q.y << 16);
    r.w = __uint_as_float(q.y & 0xffff0000u);
    return r;
}

// Fused prep, three block ranges:
//  [0, CONV_BLKS)                 : feats->bf16 convert + pos zero
//  [CONV_BLKS, +NBLK_A)           : edge partition (LDS counters, no global
//                                   atomics; payload (d%6250)<<16 | src)
//  [CONV_BLKS+NBLK_A, +BKTI_BLKS) : bucket init to N_NODES (pad target);
//                                   block 0 zeroes fb/hb pad rows (row 50000)
__global__ __launch_bounds__(256) void prep_kernel(
    const float4* __restrict__ feats, uint2* __restrict__ fb, uint2* __restrict__ hb,
    int* __restrict__ pos,
    const int* __restrict__ src, const int* __restrict__ dst,
    unsigned int* __restrict__ stage, int* __restrict__ cntg,
    int4* __restrict__ bucket4) {
    const int tid = threadIdx.x;
    if (blockIdx.x < CONV_BLKS) {
        int i = blockIdx.x * 256 + tid;      // covers exactly N_NODES*16 f4 elems
        if (i < N_NODES) pos[i] = 0;
        float4 v = feats[i];
        uint2 q;
        q.x = bf2_pack(v.x, v.y);
        q.y = bf2_pack(v.z, v.w);
        fb[i] = q;
    } else if (blockIdx.x < CONV_BLKS + NBLK_A) {
        const int pb = blockIdx.x - CONV_BLKS;
        __shared__ int cnt[NPART];
        if (tid < NPART) cnt[tid] = 0;
        __syncthreads();
        const int base = pb * ACHUNK;
        unsigned int* bstage = stage + pb * (NPART * SEG_CAP);
#pragma unroll
        for (int j = 0; j < ACHUNK / 256; ++j) {
            int i = base + j * 256 + tid;
            if (i < N_EDGES) {
                int d = dst[i];
                int s = src[i];
                int p = d / PART_N;
                unsigned int val = ((unsigned int)(d - p * PART_N) << 16) | (unsigned int)s;
                int slot = atomicAdd(&cnt[p], 1);
                if (slot < SEG_CAP) bstage[p * SEG_CAP + slot] = val;
            }
        }
        __syncthreads();
        if (tid < NPART) cntg[pb * NPART + tid] = cnt[tid];
    } else {
        const int bi = blockIdx.x - (CONV_BLKS + NBLK_A);
        int i = bi * 256 + tid;
        if (i * 4 < N_NODES * CAP) {
            int4 v;
            v.x = N_NODES; v.y = N_NODES; v.z = N_NODES; v.w = N_NODES;
            bucket4[i] = v;
        }
        if (bi == 0 && tid < 32) {   // zero pad rows for gather padding
            uint2 z; z.x = 0u; z.y = 0u;
            if (tid < 16) fb[N_NODES * 16 + tid] = z;
            else          hb[N_NODES * 16 + (tid - 16)] = z;
        }
    }
}

// Phase B: XCD-local scatter (unchanged; L2-resident per-XCD bucket writes).
__global__ __launch_bounds__(256) void scatter_bucket_kernel(
    const unsigned int* __restrict__ stage, const int* __restrict__ cntg,
    int* __restrict__ pos, int* __restrict__ bucket) {
    const int p = blockIdx.x & (NPART - 1);
    const int j = blockIdx.x >> 3;
    const int lo = p * PART_N;
    const int tid = threadIdx.x;
    for (int b = j; b < NBLK_A; b += NB_PER_PART) {
        const int c = cntg[b * NPART + p];
        const unsigned int* seg = stage + (b * NPART + p) * SEG_CAP;
        for (int i = tid; i < c; i += 256) {
            unsigned int v = seg[i];
            int d = lo + (int)(v >> 16);
            int s = (int)(v & 0xffffu);
            int slot = atomicAdd(&pos[d], 1);
            if (slot < CAP) bucket[d * CAP + slot] = s;
        }
    }
}

// Fused SAGE layer v2 (W-amortization preserved):
//  gather phase: 16-lane group (w,g) mean-aggregates node nl = w*4+g via
//    padded uniform unroll-8 (R13 winner); h stays f32 in LDS.
//  __syncthreads, lane remap: nl2 = lane>>2, opos = w*4 + (lane&3) -> each
//    wave computes output-quarter [w*4, w*4+4) for ALL 16 nodes, so unique W
//    traffic per block = 32 KB / 16 nodes, identical to the split gemm (this
//    is what R12's fusion got wrong). a-rows re-read from L1-hot global.
//  x_out is a DIFFERENT buffer than xb_in (ping-pong) -> no gather/store race.
__global__ __launch_bounds__(256) void sage_layer_kernel(
    const uint2* __restrict__ xb_in,    // 50001 bf16 rows (row 50000 = zeros)
    const int* __restrict__ pos,        // degrees
    const int* __restrict__ bucket,
    const float* __restrict__ W_self, const float* __restrict__ W_neigh,
    const float* __restrict__ bias,
    uint2* __restrict__ x_out) {        // bf16 rows, != xb_in
    __shared__ float4 hL[16][17];

    const int tid = threadIdx.x;
    const int w = tid >> 6;
    const int lane = tid & 63;
    const int g = lane >> 4;
    const int sub = lane & 15;
    const int nl = w * 4 + g;
    const int node = blockIdx.x * 16 + nl;   // exact cover

    // ---- gather phase (uniform unroll-8, padded buckets) ----
    const int deg = pos[node];
    const int cnt = (deg < CAP) ? deg : CAP;
    const int cnt8 = (cnt + 7) & ~7;
    const int* brow = bucket + node * CAP;

#define ACC4(A, R) { A.x += R.x; A.y += R.y; A.z += R.z; A.w += R.w; }
    float4 a0 = make_float4(0.f, 0.f, 0.f, 0.f);
    float4 a1 = make_float4(0.f, 0.f, 0.f, 0.f);
    float4 a2 = make_float4(0.f, 0.f, 0.f, 0.f);
    float4 a3 = make_float4(0.f, 0.f, 0.f, 0.f);
    float4 a4 = make_float4(0.f, 0.f, 0.f, 0.f);
    float4 a5 = make_float4(0.f, 0.f, 0.f, 0.f);
    float4 a6 = make_float4(0.f, 0.f, 0.f, 0.f);
    float4 a7 = make_float4(0.f, 0.f, 0.f, 0.f);
    for (int j = 0; j < cnt8; j += 8) {
        int4 i0 = *(const int4*)(brow + j);
        int4 i1 = *(const int4*)(brow + j + 4);
        float4 r0 = bf4_unpack(xb_in[i0.x * 16 + sub]);
        float4 r1 = bf4_unpack(xb_in[i0.y * 16 + sub]);
        float4 r2 = bf4_unpack(xb_in[i0.z * 16 + sub]);
        float4 r3 = bf4_unpack(xb_in[i0.w * 16 + sub]);
        float4 r4 = bf4_unpack(xb_in[i1.x * 16 + sub]);
        float4 r5 = bf4_unpack(xb_in[i1.y * 16 + sub]);
        float4 r6 = bf4_unpack(xb_in[i1.z * 16 + sub]);
        float4 r7 = bf4_unpack(xb_in[i1.w * 16 + sub]);
        ACC4(a0, r0); ACC4(a1, r1); ACC4(a2, r2); ACC4(a3, r3);
        ACC4(a4, r4); ACC4(a5, r5); ACC4(a6, r6); ACC4(a7, r7);
    }
#undef ACC4
    float4 hv;
    hv.x = ((a0.x + a1.x) + (a2.x + a3.x)) + ((a4.x + a5.x) + (a6.x + a7.x));
    hv.y = ((a0.y + a1.y) + (a2.y + a3.y)) + ((a4.y + a5.y) + (a6.y + a7.y));
    hv.z = ((a0.z + a1.z) + (a2.z + a3.z)) + ((a4.z + a5.z) + (a6.z + a7.z));
    hv.w = ((a0.w + a1.w) + (a2.w + a3.w)) + ((a4.w + a5.w) + (a6.w + a7.w));
    float inv = 1.0f / fmaxf((float)deg, 1.0f);
    hv.x *= inv; hv.y *= inv; hv.z *= inv; hv.w *= inv;
    hL[nl][sub] = hv;
    __syncthreads();

    // ---- gemm phase: lane -> (node nl2, output-quarter opos) ----
    const int nl2 = lane >> 2;
    const int opos = w * 4 + (lane & 3);
    const int node2 = blockIdx.x * 16 + nl2;
    const uint2* arow = xb_in + node2 * 16;
    const float4* hrow = &hL[nl2][0];
    const float4* Wsg = (const float4*)W_self;
    const float4* Wng = (const float4*)W_neigh;
    float4 acc = ((const float4*)bias)[opos];

#pragma unroll 4
    for (int kk = 0; kk < 16; ++kk) {
        float4 ws0 = Wsg[(kk * 4 + 0) * 16 + opos];
        float4 ws1 = Wsg[(kk * 4 + 1) * 16 + opos];
        float4 ws2 = Wsg[(kk * 4 + 2) * 16 + opos];
        float4 ws3 = Wsg[(kk * 4 + 3) * 16 + opos];
        float4 wn0 = Wng[(kk * 4 + 0) * 16 + opos];
        float4 wn1 = Wng[(kk * 4 + 1) * 16 + opos];
        float4 wn2 = Wng[(kk * 4 + 2) * 16 + opos];
        float4 wn3 = Wng[(kk * 4 + 3) * 16 + opos];
        float4 av = bf4_unpack(arow[kk]);
        float4 h4 = hrow[kk];
        acc.x += av.x * ws0.x + av.y * ws1.x + av.z * ws2.x + av.w * ws3.x
               + h4.x * wn0.x + h4.y * wn1.x + h4.z * wn2.x + h4.w * wn3.x;
        acc.y += av.x * ws0.y + av.y * ws1.y + av.z * ws2.y + av.w * ws3.y
               + h4.x * wn0.y + h4.y * wn1.y + h4.z * wn2.y + h4.w * wn3.y;
        acc.z += av.x * ws0.z + av.y * ws1.z + av.z * ws2.z + av.w * ws3.z
               + h4.x * wn0.z + h4.y * wn1.z + h4.z * wn2.z + h4.w * wn3.z;
        acc.w += av.x * ws0.w + av.y * ws1.w + av.z * ws2.w + av.w * ws3.w
               + h4.x * wn0.w + h4.y * wn1.w + h4.z * wn2.w + h4.w * wn3.w;
    }

    float rx = fmaxf(acc.x, 0.f), ry = fmaxf(acc.y, 0.f);
    float rz = fmaxf(acc.z, 0.f), rw = fmaxf(acc.w, 0.f);
    uint2 q;
    q.x = bf2_pack(rx, ry);
    q.y = bf2_pack(rz, rw);
    x_out[node2 * 16 + opos] = q;
}

// Edge dot (unchanged R11/R13): original edge order, unroll 8, int4 index
// loads, sequential out[] lines; random bf16 row reads at machine throughput.
__global__ __launch_bounds__(256) void edge_dot_kernel(
    const uint2* __restrict__ xb,       // bf16 rows, stride 16 uint2
    const int* __restrict__ src,
    const int* __restrict__ dst,
    float* __restrict__ out) {
    const int tid = threadIdx.x;
    const int grp = tid >> 4;
    const int sub = tid & 15;
    const int e0 = (blockIdx.x * 16 + grp) * 8;  // grid covers exactly N_EDGES

    int4 sa = *(const int4*)(src + e0);
    int4 sb = *(const int4*)(src + e0 + 4);
    int4 da = *(const int4*)(dst + e0);
    int4 db = *(const int4*)(dst + e0 + 4);

    float4 as0 = bf4_unpack(xb[sa.x * 16 + sub]);
    float4 ad0 = bf4_unpack(xb[da.x * 16 + sub]);
    float4 as1 = bf4_unpack(xb[sa.y * 16 + sub]);
    float4 ad1 = bf4_unpack(xb[da.y * 16 + sub]);
    float4 as2 = bf4_unpack(xb[sa.z * 16 + sub]);
    float4 ad2 = bf4_unpack(xb[da.z * 16 + sub]);
    float4 as3 = bf4_unpack(xb[sa.w * 16 + sub]);
    float4 ad3 = bf4_unpack(xb[da.w * 16 + sub]);
    float4 as4 = bf4_unpack(xb[sb.x * 16 + sub]);
    float4 ad4 = bf4_unpack(xb[db.x * 16 + sub]);
    float4 as5 = bf4_unpack(xb[sb.y * 16 + sub]);
    float4 ad5 = bf4_unpack(xb[db.y * 16 + sub]);
    float4 as6 = bf4_unpack(xb[sb.z * 16 + sub]);
    float4 ad6 = bf4_unpack(xb[db.z * 16 + sub]);
    float4 as7 = bf4_unpack(xb[sb.w * 16 + sub]);
    float4 ad7 = bf4_unpack(xb[db.w * 16 + sub]);

#define EDGE_EMIT(U, AS, AD)                                                    \
    {                                                                           \
        float p = (AS).x * (AD).x + (AS).y * (AD).y                             \
                + (AS).z * (AD).z + (AS).w * (AD).w;                            \
        p += __shfl_xor(p, 1);                                                  \
        p += __shfl_xor(p, 2);                                                  \
        p += __shfl_xor(p, 4);                                                  \
        p += __shfl_xor(p, 8);                                                  \
        if (sub == 0) {                                                         \
            float s1v = 1.f / (1.f + __expf(-p));                               \
            out[e0 + (U)] = 1.f / (1.f + __expf(-s1v));                         \
        }                                                                       \
    }
    EDGE_EMIT(0, as0, ad0);
    EDGE_EMIT(1, as1, ad1);
    EDGE_EMIT(2, as2, ad2);
    EDGE_EMIT(3, as3, ad3);
    EDGE_EMIT(4, as4, ad4);
    EDGE_EMIT(5, as5, ad5);
    EDGE_EMIT(6, as6, ad6);
    EDGE_EMIT(7, as7, ad7);
#undef EDGE_EMIT
}

extern "C" void kernel_launch(void* const* d_in, const int* in_sizes, int n_in,
                              void* d_out, int out_size, void* d_ws, size_t ws_size,
                              hipStream_t stream) {
    const float* feats = (const float*)d_in[0];
    const int* src = (const int*)d_in[1];
    const int* dst = (const int*)d_in[2];
    const float* Ws1 = (const float*)d_in[3];
    const float* Wn1 = (const float*)d_in[4];
    const float* b1 = (const float*)d_in[5];
    const float* Ws2 = (const float*)d_in[6];
    const float* Wn2 = (const float*)d_in[7];
    const float* b2 = (const float*)d_in[8];
    float* out = (float*)d_out;

    char* ws = (char*)d_ws;
    uint2* fb            = (uint2*)(ws + FB_OFF);    // feats bf16 (+pad row); then x2
    uint2* hb            = (uint2*)(ws + HB_OFF);    // x1 (+pad row)
    unsigned int* stage  = (unsigned int*)(ws + STG_OFF);
    int* cntg            = (int*)(ws + CNTG_OFF);
    int* pos             = (int*)(ws + POS_OFF);
    int* bucket          = (int*)(ws + BKT_OFF);

    prep_kernel<<<CONV_BLKS + NBLK_A + BKTI_BLKS, 256, 0, stream>>>(
        (const float4*)feats, fb, hb, pos, src, dst, stage, cntg, (int4*)bucket);
    scatter_bucket_kernel<<<NPART * NB_PER_PART, 256, 0, stream>>>(stage, cntg, pos, bucket);

    const int grid16 = N_NODES / 16;   // 3125

    // layer 1: fb (feats) -> hb (x1)
    sage_layer_kernel<<<grid16, 256, 0, stream>>>(fb, pos, bucket, Ws1, Wn1, b1, hb);
    // layer 2: hb (x1) -> fb (x2)
    sage_layer_kernel<<<grid16, 256, 0, stream>>>(hb, pos, bucket, Ws2, Wn2, b2, fb);

    edge_dot_kernel<<<N_EDGES / 128, 256, 0, stream>>>((const uint2*)fb, src, dst, out);
}

// Round 15
// 157.144 us; speedup vs baseline: 1.3030x; 1.3030x over previous
//
#include <hip/hip_runtime.h>
#include <math.h>

#define N_NODES 50000
#define N_EDGES 800000
#define D 64
#define CAP 48          // bucket capacity; deg ~ Binom(800k,1/50k), mean 16, P(>48) ~ 0
#define NPART 8         // node partitions == XCDs
#define PART_N (N_NODES / NPART)    // 6250
#define ACHUNK 2048     // edges per partition-phase block
#define NBLK_A ((N_EDGES + ACHUNK - 1) / ACHUNK)   // 391
#define SEG_CAP 448     // per-(block,part) segment capacity (mean 256, +12.8 sigma)
#define NB_PER_PART 32  // phase-B blocks per partition
#define CONV_BLKS 3125  // convert blocks in prep
#define BKTI_BLKS 2344  // bucket-init blocks in prep (int4 writes)

// ---------------- workspace layout (byte offsets, no aliasing) ----------------
// fb   @ 0        : 6.401 MB (bf16 rows 128B; 50001 rows -- row 50000 is the
//                             ZERO row for bucket padding; feats, then x1 in-place)
// hb   @ 6401024  : 6.4 MB  (bf16 rows; h, then x2 in-place)
// stage @ 12801024 : 5.61 MB ; cntg @ 18433024 ; pos @ 19201024 ; bucket @ 19401728
// total 29.0 MB (<= 32.2 MB proven available)
#define FB_OFF   0
#define HB_OFF   6401024
#define STG_OFF  12801024
#define CNTG_OFF 18433024
#define POS_OFF  19201024
#define BKT_OFF  19401728

// ---- bf16 pack/unpack helpers (RNE) ----
__device__ __forceinline__ unsigned int bf_rtn(float x) {
    unsigned int b = __float_as_uint(x);
    return (b + 0x7fffu + ((b >> 16) & 1u)) >> 16;
}
__device__ __forceinline__ unsigned int bf2_pack(float lo, float hi) {
    return bf_rtn(lo) | (bf_rtn(hi) << 16);
}
__device__ __forceinline__ float4 bf4_unpack(uint2 q) {
    float4 r;
    r.x = __uint_as_float(q.x << 16);
    r.y = __uint_as_float(q.x & 0xffff0000u);
    r.z = __uint_as_float(q.y << 16);
    r.w = __uint_as_float(q.y & 0xffff0000u);
    return r;
}

// Fused prep, three block ranges:
//  [0, CONV_BLKS)                      : feats->bf16 convert + pos zero
//  [CONV_BLKS, CONV_BLKS+NBLK_A)       : edge partition (LDS counters, no
//                                        global atomics; payload (d%6250)<<16|src)
//  [CONV_BLKS+NBLK_A, +BKTI_BLKS)      : bucket init to N_NODES (pad target);
//                                        block 0 of this range also zeroes
//                                        fb row 50000 (the pad zero-row)
__global__ __launch_bounds__(256) void prep_kernel(
    const float4* __restrict__ feats, uint2* __restrict__ fb, int* __restrict__ pos,
    const int* __restrict__ src, const int* __restrict__ dst,
    unsigned int* __restrict__ stage, int* __restrict__ cntg,
    int4* __restrict__ bucket4) {
    const int tid = threadIdx.x;
    if (blockIdx.x < CONV_BLKS) {
        int i = blockIdx.x * 256 + tid;      // covers exactly N_NODES*16 f4 elems
        if (i < N_NODES) pos[i] = 0;
        float4 v = feats[i];
        uint2 q;
        q.x = bf2_pack(v.x, v.y);
        q.y = bf2_pack(v.z, v.w);
        fb[i] = q;
    } else if (blockIdx.x < CONV_BLKS + NBLK_A) {
        const int pb = blockIdx.x - CONV_BLKS;
        __shared__ int cnt[NPART];
        if (tid < NPART) cnt[tid] = 0;
        __syncthreads();
        const int base = pb * ACHUNK;
        unsigned int* bstage = stage + pb * (NPART * SEG_CAP);
#pragma unroll
        for (int j = 0; j < ACHUNK / 256; ++j) {
            int i = base + j * 256 + tid;
            if (i < N_EDGES) {
                int d = dst[i];
                int s = src[i];
                int p = d / PART_N;
                unsigned int val = ((unsigned int)(d - p * PART_N) << 16) | (unsigned int)s;
                int slot = atomicAdd(&cnt[p], 1);
                if (slot < SEG_CAP) bstage[p * SEG_CAP + slot] = val;
            }
        }
        __syncthreads();
        if (tid < NPART) cntg[pb * NPART + tid] = cnt[tid];
    } else {
        const int bi = blockIdx.x - (CONV_BLKS + NBLK_A);
        int i = bi * 256 + tid;
        if (i * 4 < N_NODES * CAP) {
            int4 v;
            v.x = N_NODES; v.y = N_NODES; v.z = N_NODES; v.w = N_NODES;
            bucket4[i] = v;
        }
        if (bi == 0 && tid < 16) {   // zero row for pad reads
            uint2 z; z.x = 0u; z.y = 0u;
            fb[N_NODES * 16 + tid] = z;
        }
    }
}

// Phase B: XCD-local scatter (L2-resident per-XCD bucket writes).
__global__ __launch_bounds__(256) void scatter_bucket_kernel(
    const unsigned int* __restrict__ stage, const int* __restrict__ cntg,
    int* __restrict__ pos, int* __restrict__ bucket) {
    const int p = blockIdx.x & (NPART - 1);
    const int j = blockIdx.x >> 3;
    const int lo = p * PART_N;
    const int tid = threadIdx.x;
    for (int b = j; b < NBLK_A; b += NB_PER_PART) {
        const int c = cntg[b * NPART + p];
        const unsigned int* seg = stage + (b * NPART + p) * SEG_CAP;
        for (int i = tid; i < c; i += 256) {
            unsigned int v = seg[i];
            int d = lo + (int)(v >> 16);
            int s = (int)(v & 0xffffu);
            int slot = atomicAdd(&pos[d], 1);
            if (slot < CAP) bucket[d * CAP + slot] = s;
        }
    }
}

// Mean-aggregate (uniform unroll-8): buckets are padded to a multiple of 8
// with index N_NODES (a zeroed row), so the loop has NO tails and NO scalar
// path. 16 lanes per node, 16 nodes per block -> grid 3125.
__global__ __launch_bounds__(256) void gather_mean_kernel(
    const uint2* __restrict__ xb,       // bf16 rows (50001: row 50000 = zeros)
    const int* __restrict__ pos,        // degrees
    const int* __restrict__ bucket,
    uint2* __restrict__ h_out) {        // bf16 rows, stride 16 uint2
    const int tid = threadIdx.x;
    const int lane = tid & 63;
    const int g = lane >> 4;
    const int sub = lane & 15;
    const int node = blockIdx.x * 16 + (tid >> 6) * 4 + g;  // exact cover

    const int deg = pos[node];
    const int cnt = (deg < CAP) ? deg : CAP;
    const int cnt8 = (cnt + 7) & ~7;        // <= CAP = 48
    const int* brow = bucket + node * CAP;  // 16B-aligned

#define ACC4(A, R) { A.x += R.x; A.y += R.y; A.z += R.z; A.w += R.w; }
    float4 a0 = make_float4(0.f, 0.f, 0.f, 0.f);
    float4 a1 = make_float4(0.f, 0.f, 0.f, 0.f);
    float4 a2 = make_float4(0.f, 0.f, 0.f, 0.f);
    float4 a3 = make_float4(0.f, 0.f, 0.f, 0.f);
    float4 a4 = make_float4(0.f, 0.f, 0.f, 0.f);
    float4 a5 = make_float4(0.f, 0.f, 0.f, 0.f);
    float4 a6 = make_float4(0.f, 0.f, 0.f, 0.f);
    float4 a7 = make_float4(0.f, 0.f, 0.f, 0.f);
    for (int j = 0; j < cnt8; j += 8) {
        int4 i0 = *(const int4*)(brow + j);
        int4 i1 = *(const int4*)(brow + j + 4);
        float4 r0 = bf4_unpack(xb[i0.x * 16 + sub]);
        float4 r1 = bf4_unpack(xb[i0.y * 16 + sub]);
        float4 r2 = bf4_unpack(xb[i0.z * 16 + sub]);
        float4 r3 = bf4_unpack(xb[i0.w * 16 + sub]);
        float4 r4 = bf4_unpack(xb[i1.x * 16 + sub]);
        float4 r5 = bf4_unpack(xb[i1.y * 16 + sub]);
        float4 r6 = bf4_unpack(xb[i1.z * 16 + sub]);
        float4 r7 = bf4_unpack(xb[i1.w * 16 + sub]);
        ACC4(a0, r0); ACC4(a1, r1); ACC4(a2, r2); ACC4(a3, r3);
        ACC4(a4, r4); ACC4(a5, r5); ACC4(a6, r6); ACC4(a7, r7);
    }
#undef ACC4
    float4 acc;
    acc.x = ((a0.x + a1.x) + (a2.x + a3.x)) + ((a4.x + a5.x) + (a6.x + a7.x));
    acc.y = ((a0.y + a1.y) + (a2.y + a3.y)) + ((a4.y + a5.y) + (a6.y + a7.y));
    acc.z = ((a0.z + a1.z) + (a2.z + a3.z)) + ((a4.z + a5.z) + (a6.z + a7.z));
    acc.w = ((a0.w + a1.w) + (a2.w + a3.w)) + ((a4.w + a5.w) + (a6.w + a7.w));
    float inv = 1.0f / fmaxf((float)deg, 1.0f);
    uint2 q;
    q.x = bf2_pack(acc.x * inv, acc.y * inv);
    q.y = bf2_pack(acc.z * inv, acc.w * inv);
    h_out[node * 16 + sub] = q;
}

// Dense fused GEMM (R10/R11 winner structure): one wave per block, 16 nodes
// per wave (4 per lane -> W loads amortized 4x), grid 3125 -> ~12 blocks/CU.
// ALIASING (deliberate, no __restrict__): layer 1 x_out == xb_self (fb);
// layer 2 x_out == hb_in. Node n's rows are read only by its owner lanes, all
// reads precede the stores in wave program order -> race-free.
__global__ __launch_bounds__(64, 3) void sage_gemm_kernel(
    const uint2* xb_self,               // bf16 rows, stride 16 uint2
    const uint2* hb_in,                 // bf16 rows, stride 16 uint2
    const float* __restrict__ W_self, const float* __restrict__ W_neigh,
    const float* __restrict__ bias,
    uint2* x_out) {                     // bf16 rows, stride 16 uint2
    const int lane = threadIdx.x;
    const int g = lane >> 4;
    const int sub = lane & 15;
    const int nb = blockIdx.x * 16;

    const int n0 = nb + 0 * 4 + g;
    const int n1 = nb + 1 * 4 + g;
    const int n2 = nb + 2 * 4 + g;
    const int n3 = nb + 3 * 4 + g;
    const uint2* arow0 = xb_self + n0 * 16;
    const uint2* arow1 = xb_self + n1 * 16;
    const uint2* arow2 = xb_self + n2 * 16;
    const uint2* arow3 = xb_self + n3 * 16;
    const uint2* hrow0 = hb_in + n0 * 16;
    const uint2* hrow1 = hb_in + n1 * 16;
    const uint2* hrow2 = hb_in + n2 * 16;
    const uint2* hrow3 = hb_in + n3 * 16;

    const float4* Wsg = (const float4*)W_self;
    const float4* Wng = (const float4*)W_neigh;
    const float4 b4 = ((const float4*)bias)[sub];
    float4 accs0 = b4, accs1 = b4, accs2 = b4, accs3 = b4;

#pragma unroll 4
    for (int kk = 0; kk < 16; ++kk) {
        float4 ws0 = Wsg[(kk * 4 + 0) * 16 + sub];
        float4 ws1 = Wsg[(kk * 4 + 1) * 16 + sub];
        float4 ws2 = Wsg[(kk * 4 + 2) * 16 + sub];
        float4 ws3 = Wsg[(kk * 4 + 3) * 16 + sub];
        float4 wn0 = Wng[(kk * 4 + 0) * 16 + sub];
        float4 wn1 = Wng[(kk * 4 + 1) * 16 + sub];
        float4 wn2 = Wng[(kk * 4 + 2) * 16 + sub];
        float4 wn3 = Wng[(kk * 4 + 3) * 16 + sub];

#define SAGE_FMA(ACC, AROW, HROW)                                               \
        {                                                                       \
            float4 a4 = bf4_unpack((AROW)[kk]);                                 \
            float4 h4v = bf4_unpack((HROW)[kk]);                                \
            ACC.x += a4.x * ws0.x + a4.y * ws1.x + a4.z * ws2.x + a4.w * ws3.x  \
                   + h4v.x * wn0.x + h4v.y * wn1.x + h4v.z * wn2.x + h4v.w * wn3.x; \
            ACC.y += a4.x * ws0.y + a4.y * ws1.y + a4.z * ws2.y + a4.w * ws3.y  \
                   + h4v.x * wn0.y + h4v.y * wn1.y + h4v.z * wn2.y + h4v.w * wn3.y; \
            ACC.z += a4.x * ws0.z + a4.y * ws1.z + a4.z * ws2.z + a4.w * ws3.z  \
                   + h4v.x * wn0.z + h4v.y * wn1.z + h4v.z * wn2.z + h4v.w * wn3.z; \
            ACC.w += a4.x * ws0.w + a4.y * ws1.w + a4.z * ws2.w + a4.w * ws3.w  \
                   + h4v.x * wn0.w + h4v.y * wn1.w + h4v.z * wn2.w + h4v.w * wn3.w; \
        }
        SAGE_FMA(accs0, arow0, hrow0);
        SAGE_FMA(accs1, arow1, hrow1);
        SAGE_FMA(accs2, arow2, hrow2);
        SAGE_FMA(accs3, arow3, hrow3);
#undef SAGE_FMA
    }

#define SAGE_STORE(N, ACC)                                                      \
    {                                                                           \
        float rx = fmaxf(ACC.x, 0.f), ry = fmaxf(ACC.y, 0.f);                   \
        float rz = fmaxf(ACC.z, 0.f), rw = fmaxf(ACC.w, 0.f);                   \
        uint2 q; q.x = bf2_pack(rx, ry); q.y = bf2_pack(rz, rw);                \
        x_out[(N) * 16 + sub] = q;                                              \
    }
    SAGE_STORE(n0, accs0);
    SAGE_STORE(n1, accs1);
    SAGE_STORE(n2, accs2);
    SAGE_STORE(n3, accs3);
#undef SAGE_STORE
}

// Edge dot: original edge order, unroll 8, int4 index loads, sequential out[]
// lines; random bf16 row reads at machine throughput (~5.9 TB/s effective).
__global__ __launch_bounds__(256) void edge_dot_kernel(
    const uint2* __restrict__ xb,       // bf16 rows, stride 16 uint2
    const int* __restrict__ src,
    const int* __restrict__ dst,
    float* __restrict__ out) {
    const int tid = threadIdx.x;
    const int grp = tid >> 4;
    const int sub = tid & 15;
    const int e0 = (blockIdx.x * 16 + grp) * 8;  // grid covers exactly N_EDGES

    int4 sa = *(const int4*)(src + e0);
    int4 sb = *(const int4*)(src + e0 + 4);
    int4 da = *(const int4*)(dst + e0);
    int4 db = *(const int4*)(dst + e0 + 4);

    float4 as0 = bf4_unpack(xb[sa.x * 16 + sub]);
    float4 ad0 = bf4_unpack(xb[da.x * 16 + sub]);
    float4 as1 = bf4_unpack(xb[sa.y * 16 + sub]);
    float4 ad1 = bf4_unpack(xb[da.y * 16 + sub]);
    float4 as2 = bf4_unpack(xb[sa.z * 16 + sub]);
    float4 ad2 = bf4_unpack(xb[da.z * 16 + sub]);
    float4 as3 = bf4_unpack(xb[sa.w * 16 + sub]);
    float4 ad3 = bf4_unpack(xb[da.w * 16 + sub]);
    float4 as4 = bf4_unpack(xb[sb.x * 16 + sub]);
    float4 ad4 = bf4_unpack(xb[db.x * 16 + sub]);
    float4 as5 = bf4_unpack(xb[sb.y * 16 + sub]);
    float4 ad5 = bf4_unpack(xb[db.y * 16 + sub]);
    float4 as6 = bf4_unpack(xb[sb.z * 16 + sub]);
    float4 ad6 = bf4_unpack(xb[db.z * 16 + sub]);
    float4 as7 = bf4_unpack(xb[sb.w * 16 + sub]);
    float4 ad7 = bf4_unpack(xb[db.w * 16 + sub]);

#define EDGE_EMIT(U, AS, AD)                                                    \
    {                                                                           \
        float p = (AS).x * (AD).x + (AS).y * (AD).y                             \
                + (AS).z * (AD).z + (AS).w * (AD).w;                            \
        p += __shfl_xor(p, 1);                                                  \
        p += __shfl_xor(p, 2);                                                  \
        p += __shfl_xor(p, 4);                                                  \
        p += __shfl_xor(p, 8);                                                  \
        if (sub == 0) {                                                         \
            float s1v = 1.f / (1.f + __expf(-p));                               \
            out[e0 + (U)] = 1.f / (1.f + __expf(-s1v));                         \
        }                                                                       \
    }
    EDGE_EMIT(0, as0, ad0);
    EDGE_EMIT(1, as1, ad1);
    EDGE_EMIT(2, as2, ad2);
    EDGE_EMIT(3, as3, ad3);
    EDGE_EMIT(4, as4, ad4);
    EDGE_EMIT(5, as5, ad5);
    EDGE_EMIT(6, as6, ad6);
    EDGE_EMIT(7, as7, ad7);
#undef EDGE_EMIT
}

extern "C" void kernel_launch(void* const* d_in, const int* in_sizes, int n_in,
                              void* d_out, int out_size, void* d_ws, size_t ws_size,
                              hipStream_t stream) {
    const float* feats = (const float*)d_in[0];
    const int* src = (const int*)d_in[1];
    const int* dst = (const int*)d_in[2];
    const float* Ws1 = (const float*)d_in[3];
    const float* Wn1 = (const float*)d_in[4];
    const float* b1 = (const float*)d_in[5];
    const float* Ws2 = (const float*)d_in[6];
    const float* Wn2 = (const float*)d_in[7];
    const float* b2 = (const float*)d_in[8];
    float* out = (float*)d_out;

    char* ws = (char*)d_ws;
    uint2* fb            = (uint2*)(ws + FB_OFF);    // feats bf16 (+zero row), then x1
    uint2* hb            = (uint2*)(ws + HB_OFF);    // h bf16, then x2 in-place
    unsigned int* stage  = (unsigned int*)(ws + STG_OFF);
    int* cntg            = (int*)(ws + CNTG_OFF);
    int* pos             = (int*)(ws + POS_OFF);
    int* bucket          = (int*)(ws + BKT_OFF);

    prep_kernel<<<CONV_BLKS + NBLK_A + BKTI_BLKS, 256, 0, stream>>>(
        (const float4*)feats, fb, pos, src, dst, stage, cntg, (int4*)bucket);
    scatter_bucket_kernel<<<NPART * NB_PER_PART, 256, 0, stream>>>(stage, cntg, pos, bucket);

    const int grid16 = N_NODES / 16;   // 3125

    // layer 1: h <- mean(feats); x1 <- gemm (in-place over fb)
    gather_mean_kernel<<<grid16, 256, 0, stream>>>(fb, pos, bucket, hb);
    sage_gemm_kernel<<<grid16, 64, 0, stream>>>(fb, hb, Ws1, Wn1, b1, fb);
    // layer 2: h <- mean(x1); x2 <- gemm (in-place over hb)
    gather_mean_kernel<<<grid16, 256, 0, stream>>>(fb, pos, bucket, hb);
    sage_gemm_kernel<<<grid16, 64, 0, stream>>>(fb, hb, Ws2, Wn2, b2, hb);

    edge_dot_kernel<<<N_EDGES / 128, 256, 0, stream>>>((const uint2*)hb, src, dst, out);
}